// Round 16
// baseline (5585.953 us; speedup 1.0000x reference)
//
#include <hip/hip_runtime.h>
#include <hip/hip_bf16.h>

// StackedMatchLSTM on MI355X — single-exchange scan: h + att-partials
// published together as seq-stamped 8B payloads (one LLC RT per step).
// B=32, TP=512, TQ=64, DP=DQ=H=AH=256, NL=2.
// Scan: 256 WGs (8 slices x 32 batches) x 512 threads. Slice j owns h-elems
// [32j,32j+32) + their 128 gate cols. Per step, slice j publishes its h slice
// AND partial_j[a] = sum_{k in slice} h1[k]*Wr[k][a] (256 f). Consumers
// gather 1 h + 8 partials per thread in ONE concurrent spin (seq-stamped,
// self-validating -> no ordering requirements; multi-wave publish proven r15).
// Scores+softmax fully local (qWq bf16 in LDS). Weights LDS-resident,
// consumption-ordered [iter][tid] layouts (0 bank conflicts, proven r13/14).

#define NB 32
#define TPL 512
#define TQL 64
#define DD 256      // DP = DQ = H = AH
#define H4 1024     // 4*H
#define NC 1280     // AH + 4H
#define NS 8        // slices per batch
#define GC 128      // gate cols per slice

typedef unsigned long long u64;

__device__ __forceinline__ float fast_tanh(float x) {
  float xc = fminf(fmaxf(x, -9.f), 9.f);
  float e = __expf(2.f * xc);
  return (e - 1.f) * __builtin_amdgcn_rcpf(e + 1.f);
}
__device__ __forceinline__ float fast_sigmoid(float x) {
  return __builtin_amdgcn_rcpf(1.f + __expf(-x));
}
__device__ __forceinline__ float bflo(unsigned int w) { return __uint_as_float(w << 16); }
__device__ __forceinline__ float bfhi(unsigned int w) { return __uint_as_float(w & 0xffff0000u); }
__device__ __forceinline__ unsigned int packbf(float a, float b) {
  unsigned int lo = __hip_bfloat16_raw(__float2bfloat16(a)).x;
  unsigned int hi = __hip_bfloat16_raw(__float2bfloat16(b)).x;
  return lo | (hi << 16);
}

// ---- seq-stamped payload exchange (relaxed agent atomics, LLC-coherent) -----
__device__ __forceinline__ u64 aload64(const u64* p) {
  return __hip_atomic_load(p, __ATOMIC_RELAXED, __HIP_MEMORY_SCOPE_AGENT);
}
__device__ __forceinline__ void astore64(u64* p, u64 v) {
  __hip_atomic_store(p, v, __ATOMIC_RELAXED, __HIP_MEMORY_SCOPE_AGENT);
}
__device__ __forceinline__ u64 packsv(float val, unsigned int seq) {
  return ((u64)seq << 32) | (u64)__float_as_uint(val);
}
__device__ __forceinline__ float u2f(u64 v) {
  return __uint_as_float((unsigned int)v);
}

// permuted xpl cols: [0,256) att (shared) | per slice j: 128 gate cols f|i|o|g
__device__ __forceinline__ int perm_col(int c) {
  if (c < DD) return c;
  int cc = c - DD;
  int g = cc >> 8;          // 0..3 = f,i,o,g
  int m = cc & 255;         // h-elem
  return DD + (m >> 5) * GC + (g << 5) + (m & 31);
}

// ---- weight prep ------------------------------------------------------------
__global__ __launch_bounds__(256) void pack_weights(
    const float* __restrict__ Wp, const float* __restrict__ Wq,
    const float* __restrict__ Wl,
    float* __restrict__ wx, float* __restrict__ wqv)
{
  int d = blockIdx.y;
  int idx = blockIdx.x * 256 + threadIdx.x;
  if (idx >= DD * NC) return;
  int k = idx / NC, j = idx % NC;
  int o = d * DD * NC + idx;
  const float* Wld = Wl + (size_t)d * 768 * H4;
  if (j < DD) {
    int s = d * DD * DD + k * DD + j;
    wx[o] = Wp[s]; wqv[o] = Wq[s];
  } else {
    int c = j - DD;
    wx[o]  = Wld[(size_t)k * H4 + c];
    wqv[o] = Wld[(size_t)(DD + k) * H4 + c];
  }
}

// watk[((d*8+j)*32 + k)*256 + a] = bf16(Wr[d][32j+k][a])  (ushort)
__global__ __launch_bounds__(256) void pack_watk(
    const float* __restrict__ Wr, unsigned short* __restrict__ watk)
{
  int idx = blockIdx.x * 256 + threadIdx.x;       // 2*8*32*256 = 131072
  if (idx >= 2 * NS * 32 * 256) return;
  int a = idx & 255; int r = idx >> 8;
  int k = r & 31; r >>= 5;
  int j = r & 7; int d = r >> 3;
  float v = Wr[((size_t)d * DD + (j << 5) + k) * DD + a];
  watk[idx] = __hip_bfloat16_raw(__float2bfloat16(v)).x;
}

// gatel, consumption order: [(d*8+j)][i(32)][slot(256)], slot: gcol=slot>>1,
// gh=slot&1; kq = i*2+gh (interleaved). uint2 = k's {4kq..4kq+3} of col gcol.
__global__ __launch_bounds__(256) void pack_gatel(
    const float* __restrict__ Wl, uint2* __restrict__ gatel)
{
  int idx = blockIdx.x * 256 + threadIdx.x;       // 2*8*32*256 = 131072
  if (idx >= 2 * NS * 32 * 256) return;
  int slot = idx & 255; int r = idx >> 8;
  int i = r & 31; r >>= 5;
  int j = r & 7; int d = r >> 3;
  int gcol = slot >> 1, gh = slot & 1;
  int kq = i * 2 + gh;
  int g = gcol >> 5, pos = gcol & 31;
  float v[4];
  #pragma unroll
  for (int kr = 0; kr < 4; ++kr) {
    int k = kq * 4 + kr;
    v[kr] = Wl[((size_t)d * 768 + 512 + k) * H4 + (g << 8) + (j << 5) + pos];
  }
  gatel[idx] = make_uint2(packbf(v[0], v[1]), packbf(v[2], v[3]));
}

// ---- C[M][1280] = A[M][256] @ B[256][1280], fp32 ----------------------------
template <bool PERM>
__global__ __launch_bounds__(256) void sgemm(
    const float* __restrict__ A, const float* __restrict__ Bm,
    float* __restrict__ C)
{
  __shared__ float As[16][65];
  __shared__ float Bs[16][64];
  int tid = threadIdx.x;
  int tx = tid & 15, ty = tid >> 4;
  int col0 = blockIdx.x * 64, row0 = blockIdx.y * 64;
  float acc[4][4] = {};
  for (int kt = 0; kt < DD; kt += 16) {
    #pragma unroll
    for (int i = 0; i < 4; ++i) {
      int e = tid + i * 256;
      As[e & 15][e >> 4] = A[(size_t)(row0 + (e >> 4)) * DD + kt + (e & 15)];
      Bs[e >> 6][e & 63] = Bm[(size_t)(kt + (e >> 6)) * NC + col0 + (e & 63)];
    }
    __syncthreads();
    #pragma unroll
    for (int kk = 0; kk < 16; ++kk) {
      float a[4], bv[4];
      #pragma unroll
      for (int i = 0; i < 4; ++i) a[i] = As[kk][ty * 4 + i];
      #pragma unroll
      for (int jj = 0; jj < 4; ++jj) bv[jj] = Bs[kk][tx * 4 + jj];
      #pragma unroll
      for (int i = 0; i < 4; ++i)
        #pragma unroll
        for (int jj = 0; jj < 4; ++jj)
          acc[i][jj] = fmaf(a[i], bv[jj], acc[i][jj]);
    }
    __syncthreads();
  }
  #pragma unroll
  for (int i = 0; i < 4; ++i)
    #pragma unroll
    for (int jj = 0; jj < 4; ++jj) {
      int c = col0 + tx * 4 + jj;
      int cc = PERM ? perm_col(c) : c;
      C[(size_t)(row0 + ty * 4 + i) * NC + cc] = acc[i][jj];
    }
}

// ---- scan: 256 WGs x 512 threads --------------------------------------------
__global__ __launch_bounds__(512, 1) void scan(
    const float* __restrict__ xpl,    // [NB*TP][NC] permuted cols
    const float* __restrict__ qv,     // [NB*TQ][NC] plain (this layer)
    const unsigned short* __restrict__ watk,  // [8][32][256] this layer
    const uint2* __restrict__ gatel,          // [8][32][256] this layer
    const float* __restrict__ wa,     // [256]
    const float* __restrict__ bias_f,
    const float* __restrict__ bias_iog,
    const float* __restrict__ mask_p,
    const float* __restrict__ mask_q,
    u64* __restrict__ xch_p,          // [NB][NS][256] seq-stamped att partials
    u64* __restrict__ xch_h,          // [NB][256]    seq-stamped h
    float* __restrict__ out,          // [NB*TP][256]
    int lbase)                        // layer*TPL
{
  const int bid = blockIdx.x;
  const int j = bid & 7, b = bid >> 3;
  const int tid = threadIdx.x;
  const int lane = tid & 63;

  __shared__ uint2 wg_l[32][256];         // 64 KB gate weights, [iter][tid]
  __shared__ unsigned short watk_l[32][256]; // 16 KB att k-slice, [k][a]
  __shared__ unsigned int qT[TQL][129];   // 33 KB qWq bf16 pairs
  __shared__ unsigned int vl_l[GC][33];   // 16.9 KB Vl bf16 pairs
  __shared__ __align__(16) float h_lds[DD];
  __shared__ float hxa[DD];               // x_att + sum of partials
  __shared__ float xg_s[GC];
  __shared__ float wa_s[DD];
  __shared__ float sc_part[4][66];
  __shared__ float al_s[TQL];
  __shared__ float pre_s[GC], bias_s[GC];
  __shared__ float h1_s[32];

  const float* qv_b = qv + (size_t)b * TQL * NC;
  u64* xch_p_b = xch_p + b * (NS * DD);
  u64* xch_h_b = xch_h + b * DD;

  // ---- one-time preload
  {
    const uint2* gp = gatel + (size_t)j * 32 * 256;
    for (int i = tid; i < 32 * 256; i += 512) wg_l[i >> 8][i & 255] = gp[i];
    const unsigned short* ap = watk + (size_t)j * 32 * 256;
    for (int i = tid; i < 32 * 256; i += 512) watk_l[i >> 8][i & 255] = ap[i];
    for (int i = tid; i < TQL * 128; i += 512) {
      int tq = i >> 7, aw = i & 127;
      qT[tq][aw] = packbf(qv_b[(size_t)tq * NC + 2 * aw],
                          qv_b[(size_t)tq * NC + 2 * aw + 1]);
    }
    for (int i = tid; i < GC * 32; i += 512) {
      int col = i >> 5, tw = i & 31;
      int g = col >> 5, m = (j << 5) + (col & 31);
      float v0 = qv_b[(size_t)(2 * tw) * NC + DD + (g << 8) + m];
      float v1 = qv_b[(size_t)(2 * tw + 1) * NC + DD + (g << 8) + m];
      vl_l[col][tw] = packbf(v0, v1);
    }
    for (int i = tid; i < DD; i += 512) wa_s[i] = wa[i];
    if (tid < GC) {
      int g = tid >> 5, m = (j << 5) + (tid & 31);
      bias_s[tid] = (g == 0) ? bias_f[m] : bias_iog[((g - 1) << 8) + m];
    }
  }
  float mq = mask_q[b * TQL + lane];    // softmax mask (wave 0, lane = tq)
  float cv = 0.f;                       // cell state, wave 0 lanes < 32
  __syncthreads();

  const int gcol = tid >> 1, gh = tid & 1;   // threads 0..255 gate/pre roles

  for (int t = 0; t < TPL; ++t) {
    const float* xrow = xpl + ((size_t)b * TPL + t) * NC;
    float xv = 0.f;
    if (tid < DD) xv = xrow[tid];                          // att col
    else if (tid < DD + GC) xv = xrow[DD + j * GC + (tid - DD)];
    float mtv = (tid < 32) ? mask_p[b * TPL + t] : 0.f;
    const unsigned int hseq = (unsigned int)(lbase + t);   // published at t-1
    const unsigned int sseq = (unsigned int)(lbase + t + 1);

    __syncthreads();                   // B0: prev-step LDS reads done
    // ---- gather: 1 h + 8 partials per thread, one concurrent stamped spin
    if (tid < DD) {
      float hv = 0.f, acc = xv;
      if (t > 0) {
        const u64* pp = xch_p_b + tid;
        const u64* ph = xch_h_b + tid;
        u64 v[9];
        #pragma unroll
        for (int q = 0; q < 8; ++q) v[q] = aload64(pp + q * DD);
        v[8] = aload64(ph);
        int guard = 0;
        for (;;) {
          bool ok = true;
          #pragma unroll
          for (int q = 0; q < 8; ++q)
            if ((unsigned int)(v[q] >> 32) != hseq) { ok = false; v[q] = aload64(pp + q * DD); }
          if ((unsigned int)(v[8] >> 32) != hseq) { ok = false; v[8] = aload64(ph); }
          if (ok) break;
          __builtin_amdgcn_s_sleep(1);
          if (++guard > (1 << 24)) break;
        }
        hv = u2f(v[8]);
        acc += ((u2f(v[0]) + u2f(v[1])) + (u2f(v[2]) + u2f(v[3]))) +
               ((u2f(v[4]) + u2f(v[5])) + (u2f(v[6]) + u2f(v[7])));
      }
      h_lds[tid] = hv;
      hxa[tid] = acc;
    } else if (tid < DD + GC) {
      xg_s[tid - DD] = xv;
    }
    __syncthreads();                   // B1: h_lds, hxa, xg ready

    // ---- gate GEMV (threads 0..255) || full scores (threads 256..511)
    float hwg = 0.f;
    if (tid < DD) {
      #pragma unroll
      for (int i = 0; i < 32; ++i) {
        int kq = i * 2 + gh;                     // interleaved k-split
        uint2 w = wg_l[i][tid];
        float4 h0 = *(const float4*)&h_lds[kq * 4];
        hwg = fmaf(h0.x, bflo(w.x), hwg); hwg = fmaf(h0.y, bfhi(w.x), hwg);
        hwg = fmaf(h0.z, bflo(w.y), hwg); hwg = fmaf(h0.w, bfhi(w.y), hwg);
      }
      hwg += __shfl_xor(hwg, 1);       // both partners hold full hw_gate[gcol]
    } else {
      int wv = (tid >> 6) - 4;         // 0..3 -> aw range [32wv, 32wv+32)
      int tq = lane;
      float p = 0.f;
      #pragma unroll
      for (int i = 0; i < 32; ++i) {
        int aw = wv * 32 + i;
        unsigned int q2 = qT[tq][aw];
        int a0 = 2 * aw, a1 = a0 + 1;
        p = fmaf(fast_tanh(bflo(q2) + hxa[a0]), wa_s[a0], p);
        p = fmaf(fast_tanh(bfhi(q2) + hxa[a1]), wa_s[a1], p);
      }
      sc_part[wv][tq] = p;
    }
    __syncthreads();                   // B2: sc_part ready

    // ---- softmax (wave 0)
    if (tid < TQL) {
      float v = (sc_part[0][tid] + sc_part[1][tid]) +
                (sc_part[2][tid] + sc_part[3][tid]);
      v = (mq > 0.f) ? v : -1e9f;
      float m = v;
      #pragma unroll
      for (int off = 32; off > 0; off >>= 1) m = fmaxf(m, __shfl_xor(m, off));
      float p = __expf(v - m);
      float su = p;
      #pragma unroll
      for (int off = 32; off > 0; off >>= 1) su += __shfl_xor(su, off);
      al_s[tid] = p * __builtin_amdgcn_rcpf(su);
    }
    __syncthreads();                   // B3: al ready

    // ---- pre: threads 0..255 (hold hwg): alpha@Vl 2-way tq split
    if (tid < DD) {
      float d0 = 0.f, d1 = 0.f;
      #pragma unroll
      for (int i = 0; i < 16; ++i) {
        int tw = gh * 16 + i;
        unsigned int v = vl_l[gcol][tw];
        d0 = fmaf(al_s[2 * tw], bflo(v), d0);
        d1 = fmaf(al_s[2 * tw + 1], bfhi(v), d1);
      }
      float dd = d0 + d1;
      dd += __shfl_xor(dd, 1);
      if (gh == 0)
        pre_s[gcol] = hwg + dd + xg_s[gcol] + bias_s[gcol];
    }
    __syncthreads();                   // B4: pre ready

    // ---- gates (wave 0 lanes 0..31) -> h1 -> publish h + stage h1 in LDS
    if (tid < 32) {
      float f  = pre_s[tid];
      float ii = pre_s[32 + tid];
      float oo = pre_s[64 + tid];
      float g  = pre_s[96 + tid];
      int m = (j << 5) + tid;
      float c0 = cv, h0 = h_lds[m];
      float c1 = fast_sigmoid(f) * c0 + fast_sigmoid(ii) * fast_tanh(g);
      c1 = c1 * mtv + c0 * (1.f - mtv);
      float h1 = fast_sigmoid(oo) * fast_tanh(c1);
      h1 = h1 * mtv + h0 * (1.f - mtv);
      cv = c1;
      h1_s[tid] = h1;
      astore64(xch_h_b + m, packsv(h1, sseq));
      out[((size_t)b * TPL + t) * DD + m] = h1;
    }
    __syncthreads();                   // B5: h1_s ready

    // ---- att-partial GEMV (threads 0..255, 1 col each) + stamped publish
    if (tid < DD) {
      float part = 0.f;
      #pragma unroll
      for (int k = 0; k < 32; ++k) {
        float wf = __uint_as_float((unsigned int)watk_l[k][tid] << 16);
        part = fmaf(h1_s[k], wf, part);
      }
      astore64(xch_p_b + (j << 8) + tid, packsv(part, sseq));
    }
    // no trailing barrier: next iteration's B0 orders LDS reuse
  }
}

// -----------------------------------------------------------------------------
extern "C" void kernel_launch(void* const* d_in, const int* in_sizes, int n_in,
                              void* d_out, int out_size, void* d_ws, size_t ws_size,
                              hipStream_t stream) {
  const float* input_p  = (const float*)d_in[0];
  const float* mask_p   = (const float*)d_in[1];
  const float* input_q  = (const float*)d_in[2];
  const float* mask_q   = (const float*)d_in[3];
  const float* W_att_p  = (const float*)d_in[4];
  const float* W_att_q  = (const float*)d_in[5];
  const float* W_att_r  = (const float*)d_in[6];
  const float* w_att    = (const float*)d_in[7];
  const float* W_lstm   = (const float*)d_in[8];
  const float* bias_f   = (const float*)d_in[9];
  const float* bias_iog = (const float*)d_in[10];
  float* out = (float*)d_out;
  float* ws  = (float*)d_ws;
  (void)ws_size; (void)in_sizes; (void)n_in; (void)out_size;

  const size_t SZ_XPL  = (size_t)NB * TPL * NC;
  const size_t SZ_QV   = (size_t)NB * TQL * NC;
  const size_t SZ_W    = (size_t)DD * NC;
  const size_t SZ_WATK = (size_t)NS * 32 * 256;   // ushort per layer
  const size_t SZ_GATL = (size_t)NS * 32 * 256;   // uint2 per layer

  float* ws_xpl = ws;
  float* ws_qv  = ws_xpl + SZ_XPL;
  float* ws_wx  = ws_qv  + 2 * SZ_QV;
  float* ws_wqv = ws_wx  + 2 * SZ_W;
  float* ws_o0  = ws_wqv + 2 * SZ_W;
  unsigned short* ws_watk = (unsigned short*)(ws_o0 + (size_t)NB * TPL * DD);
  uint2* ws_gatl = (uint2*)(ws_watk + 2 * SZ_WATK);
  u64*   ws_xp   = (u64*)(ws_gatl + 2 * SZ_GATL);    // [NB][8][256] stamped
  u64*   ws_xh   = ws_xp + NB * NS * DD;             // [NB][256]   stamped

  dim3 gpack((DD * NC + 255) / 256, 2);
  pack_weights<<<gpack, 256, 0, stream>>>(W_att_p, W_att_q, W_lstm, ws_wx, ws_wqv);
  pack_watk<<<(2 * NS * 32 * 256 + 255) / 256, 256, 0, stream>>>(W_att_r, ws_watk);
  pack_gatel<<<(2 * NS * 32 * 256 + 255) / 256, 256, 0, stream>>>(W_lstm, ws_gatl);
  hipMemsetAsync(ws_xp, 0, (NB * NS * DD + NB * DD) * sizeof(u64), stream);

  for (int d = 0; d < 2; ++d) {
    dim3 g(NC / 64, (NB * TQL) / 64);
    sgemm<false><<<g, 256, 0, stream>>>(input_q, ws_wqv + d * SZ_W, ws_qv + d * SZ_QV);
  }

  // layer 0
  {
    dim3 g(NC / 64, (NB * TPL) / 64);
    sgemm<true><<<g, 256, 0, stream>>>(input_p, ws_wx, ws_xpl);
    scan<<<NB * NS, 512, 0, stream>>>(ws_xpl, ws_qv, ws_watk, ws_gatl,
                                      w_att, bias_f, bias_iog, mask_p, mask_q,
                                      ws_xp, ws_xh, ws_o0, 0);
  }
  // layer 1
  {
    dim3 g(NC / 64, (NB * TPL) / 64);
    sgemm<true><<<g, 256, 0, stream>>>(ws_o0, ws_wx + SZ_W, ws_xpl);
    scan<<<NB * NS, 512, 0, stream>>>(ws_xpl, ws_qv + SZ_QV, ws_watk + SZ_WATK,
                                      ws_gatl + SZ_GATL, w_att + DD, bias_f + DD,
                                      bias_iog + 3 * DD, mask_p, mask_q,
                                      ws_xp, ws_xh, out, TPL);
  }
}

// Round 17
// 4308.030 us; speedup vs baseline: 1.2966x; 1.2966x over previous
//
#include <hip/hip_runtime.h>
#include <hip/hip_bf16.h>

// StackedMatchLSTM on MI355X — r14 structure, 6 barriers/step.
// B=32, TP=512, TQ=64, DP=DQ=H=AH=256, NL=2.
// Scan: 256 WGs (8 slices x 32 batches) x 512 threads. Slice j owns 32 att
// cols + 128 gate cols; weights LDS-resident (bf16, consumption-ordered ->
// 0 bank conflicts). Per step: spin-load h -> att GEMV (in-wave shfl reduce)
// -> scores -> {publish scores, gate GEMV (hides score RT), spin-load scores
// into gat[]} -> replicated softmax (all waves, alpha in regs) + pre ->
// gates -> publish h. Exchange: r14's proven seq-stamped 8B relaxed agent
// atomics (self-validating; multi-wave publish proven r15/16).

#define NB 32
#define TPL 512
#define TQL 64
#define DD 256      // DP = DQ = H = AH
#define H4 1024     // 4*H
#define NC 1280     // AH + 4H
#define NS 8        // slices per batch
#define SC 160      // xpl cols per slice = 32 att + 128 gate
#define GC 128      // gate cols per slice

typedef unsigned long long u64;

__device__ __forceinline__ float fast_tanh(float x) {
  float xc = fminf(fmaxf(x, -9.f), 9.f);
  float e = __expf(2.f * xc);
  return (e - 1.f) * __builtin_amdgcn_rcpf(e + 1.f);
}
__device__ __forceinline__ float fast_sigmoid(float x) {
  return __builtin_amdgcn_rcpf(1.f + __expf(-x));
}
__device__ __forceinline__ float bflo(unsigned int w) { return __uint_as_float(w << 16); }
__device__ __forceinline__ float bfhi(unsigned int w) { return __uint_as_float(w & 0xffff0000u); }
__device__ __forceinline__ unsigned int packbf(float a, float b) {
  unsigned int lo = __hip_bfloat16_raw(__float2bfloat16(a)).x;
  unsigned int hi = __hip_bfloat16_raw(__float2bfloat16(b)).x;
  return lo | (hi << 16);
}

// ---- seq-stamped payload exchange (relaxed agent atomics, LLC-coherent) -----
__device__ __forceinline__ u64 aload64(const u64* p) {
  return __hip_atomic_load(p, __ATOMIC_RELAXED, __HIP_MEMORY_SCOPE_AGENT);
}
__device__ __forceinline__ void astore64(u64* p, u64 v) {
  __hip_atomic_store(p, v, __ATOMIC_RELAXED, __HIP_MEMORY_SCOPE_AGENT);
}
__device__ __forceinline__ u64 packsv(float val, unsigned int seq) {
  return ((u64)seq << 32) | (u64)__float_as_uint(val);
}
__device__ __forceinline__ float spinload(const u64* p, unsigned int seq) {
  u64 v = aload64(p);
  int guard = 0;
  while ((unsigned int)(v >> 32) != seq) {
    __builtin_amdgcn_s_sleep(1);
    v = aload64(p);
    if (++guard > (1 << 24)) break;   // bail instead of hanging the harness
  }
  return __uint_as_float((unsigned int)v);
}

// permuted xpl cols: slice-major blocks of 160: 32 att | f|i|o|g x32
__device__ __forceinline__ int perm_col(int c) {
  if (c < DD) return (c >> 5) * SC + (c & 31);
  int cc = c - DD;
  int g = cc >> 8;          // 0..3 = f,i,o,g
  int m = cc & 255;         // h-elem
  return (m >> 5) * SC + 32 + (g << 5) + (m & 31);
}

// ---- weight prep ------------------------------------------------------------
__global__ __launch_bounds__(256) void pack_weights(
    const float* __restrict__ Wp, const float* __restrict__ Wq,
    const float* __restrict__ Wl,
    float* __restrict__ wx, float* __restrict__ wqv)
{
  int d = blockIdx.y;
  int idx = blockIdx.x * 256 + threadIdx.x;
  if (idx >= DD * NC) return;
  int k = idx / NC, j = idx % NC;
  int o = d * DD * NC + idx;
  const float* Wld = Wl + (size_t)d * 768 * H4;
  if (j < DD) {
    int s = d * DD * DD + k * DD + j;
    wx[o] = Wp[s]; wqv[o] = Wq[s];
  } else {
    int c = j - DD;
    wx[o]  = Wld[(size_t)k * H4 + c];
    wqv[o] = Wld[(size_t)(DD + k) * H4 + c];
  }
}

// attl in-wave layout: [(d*8+j)][i(8)][tid(256)], tid: col=tid>>3, q=tid&7.
// uint2 = bf16 k's {i*32+q*4 .. +3} of att col (32j + col).
__global__ __launch_bounds__(256) void pack_attl(
    const float* __restrict__ Wr, uint2* __restrict__ attl)
{
  int idx = blockIdx.x * 256 + threadIdx.x;       // 2*8*8*256 = 32768
  if (idx >= 2 * NS * 8 * 256) return;
  int tid = idx & 255; int r = idx >> 8;
  int i = r & 7; r >>= 3;
  int j = r & 7; int d = r >> 3;
  int col = tid >> 3, q = tid & 7;
  int kb = i * 32 + q * 4;
  float v[4];
  #pragma unroll
  for (int kr = 0; kr < 4; ++kr)
    v[kr] = Wr[((size_t)d * DD + kb + kr) * DD + (j << 5) + col];
  attl[idx] = make_uint2(packbf(v[0], v[1]), packbf(v[2], v[3]));
}

// gatel, consumption order: [(d*8+j)][i(16)][slot(512)], slot: gcol=slot>>2,
// gq=slot&3. uint2 = k's {4kq..4kq+3} of gate col gcol, kq = i*4 + gq.
__global__ __launch_bounds__(256) void pack_gatel(
    const float* __restrict__ Wl, uint2* __restrict__ gatel)
{
  int idx = blockIdx.x * 256 + threadIdx.x;       // 2*8*16*512 = 131072
  if (idx >= 2 * NS * 16 * 512) return;
  int slot = idx & 511; int r = idx >> 9;
  int i = r & 15; r >>= 4;
  int j = r & 7; int d = r >> 3;
  int gcol = slot >> 2, gq = slot & 3;
  int kq = i * 4 + gq;
  int g = gcol >> 5, pos = gcol & 31;
  float v[4];
  #pragma unroll
  for (int kr = 0; kr < 4; ++kr) {
    int k = kq * 4 + kr;
    v[kr] = Wl[((size_t)d * 768 + 512 + k) * H4 + (g << 8) + (j << 5) + pos];
  }
  gatel[idx] = make_uint2(packbf(v[0], v[1]), packbf(v[2], v[3]));
}

// ---- C[M][1280] = A[M][256] @ B[256][1280], fp32 ----------------------------
template <bool PERM>
__global__ __launch_bounds__(256) void sgemm(
    const float* __restrict__ A, const float* __restrict__ Bm,
    float* __restrict__ C)
{
  __shared__ float As[16][65];
  __shared__ float Bs[16][64];
  int tid = threadIdx.x;
  int tx = tid & 15, ty = tid >> 4;
  int col0 = blockIdx.x * 64, row0 = blockIdx.y * 64;
  float acc[4][4] = {};
  for (int kt = 0; kt < DD; kt += 16) {
    #pragma unroll
    for (int i = 0; i < 4; ++i) {
      int e = tid + i * 256;
      As[e & 15][e >> 4] = A[(size_t)(row0 + (e >> 4)) * DD + kt + (e & 15)];
      Bs[e >> 6][e & 63] = Bm[(size_t)(kt + (e >> 6)) * NC + col0 + (e & 63)];
    }
    __syncthreads();
    #pragma unroll
    for (int kk = 0; kk < 16; ++kk) {
      float a[4], bv[4];
      #pragma unroll
      for (int i = 0; i < 4; ++i) a[i] = As[kk][ty * 4 + i];
      #pragma unroll
      for (int jj = 0; jj < 4; ++jj) bv[jj] = Bs[kk][tx * 4 + jj];
      #pragma unroll
      for (int i = 0; i < 4; ++i)
        #pragma unroll
        for (int jj = 0; jj < 4; ++jj)
          acc[i][jj] = fmaf(a[i], bv[jj], acc[i][jj]);
    }
    __syncthreads();
  }
  #pragma unroll
  for (int i = 0; i < 4; ++i)
    #pragma unroll
    for (int jj = 0; jj < 4; ++jj) {
      int c = col0 + tx * 4 + jj;
      int cc = PERM ? perm_col(c) : c;
      C[(size_t)(row0 + ty * 4 + i) * NC + cc] = acc[i][jj];
    }
}

// ---- scan: 256 WGs x 512 threads, weights LDS-resident ----------------------
__global__ __launch_bounds__(512, 1) void scan(
    const float* __restrict__ xpl,    // [NB*TP][NC] permuted cols
    const float* __restrict__ qv,     // [NB*TQ][NC] plain (this layer)
    const uint2* __restrict__ attl,   // this layer's [8][8][256]
    const uint2* __restrict__ gatel,  // this layer's [8][16][512]
    const float* __restrict__ wa,     // [256]
    const float* __restrict__ bias_f,
    const float* __restrict__ bias_iog,
    const float* __restrict__ mask_p,
    const float* __restrict__ mask_q,
    u64* __restrict__ xch_s,          // [NB][NS][64] seq-stamped scores
    u64* __restrict__ xch_h,          // [NB][256]  seq-stamped h
    float* __restrict__ out,          // [NB*TP][256]
    int lbase)                        // layer*TPL
{
  const int bid = blockIdx.x;
  const int j = bid & 7, b = bid >> 3;
  const int tid = threadIdx.x;
  const int lane = tid & 63;

  __shared__ uint2 wg_l[16][512];        // 64 KB gate weights, [iter][tid]
  __shared__ uint2 wat2[8][256];         // 16 KB att weights, in-wave layout
  __shared__ unsigned int vl_l[8][512];  // 16 KB Vl bf16 pairs, [iter][tid]
  __shared__ float qT[32][65];           //  8.3 KB qWq^T (own att cols)
  __shared__ __align__(16) float h_lds[DD];
  __shared__ float xsl[SC];
  __shared__ float hw_att[32], waa[32];
  __shared__ float sc_part[8][TQL];      // own-slice score sub-partials
  __shared__ float gat[7][TQL];          // gathered other-slice partials
  __shared__ float pre_s[GC], bias_s[GC];

  const float* qv_b = qv + (size_t)b * TQL * NC;
  u64* xch_s_b = xch_s + b * (NS * TQL);
  u64* xch_h_b = xch_h + b * DD;

  // ---- one-time preload: weights + per-batch activations into LDS
  {
    const uint2* gp = gatel + (size_t)j * 16 * 512;
    for (int i = tid; i < 16 * 512; i += 512) wg_l[i >> 9][i & 511] = gp[i];
    const uint2* ap = attl + (size_t)j * 8 * 256;
    for (int i = tid; i < 8 * 256; i += 512) wat2[i >> 8][i & 255] = ap[i];
    for (int i = tid; i < TQL * 32; i += 512) {
      int tq = i >> 5, a = i & 31;
      qT[a][tq] = qv_b[(size_t)tq * NC + (j << 5) + a];
    }
    for (int f = tid; f < 8 * 512; f += 512) {
      int ii = f >> 9, slot = f & 511;
      int gcol = slot >> 2, gq = slot & 3;
      int tw = gq * 8 + ii;
      int g = gcol >> 5, m = (j << 5) + (gcol & 31);
      float v0 = qv_b[(size_t)(2 * tw) * NC + DD + (g << 8) + m];
      float v1 = qv_b[(size_t)(2 * tw + 1) * NC + DD + (g << 8) + m];
      vl_l[ii][slot] = packbf(v0, v1);
    }
    if (tid < 32) waa[tid] = wa[(j << 5) + tid];
    if (tid < GC) {
      int g = tid >> 5, m = (j << 5) + (tid & 31);
      bias_s[tid] = (g == 0) ? bias_f[m] : bias_iog[((g - 1) << 8) + m];
    }
  }
  float mq = mask_q[b * TQL + lane];    // all waves (replicated softmax)
  float cv = 0.f;                       // cell state, wave 0 lanes < 32
  __syncthreads();

  // role indices
  const int stq = tid & 63, ssub = tid >> 6;      // scores: 8 subs x 4 cols
  const int gcol = tid >> 2, gq = tid & 3;        // gate/pre: 4-way split
  // spin role: threads 64..511 gather the 7 OTHER slices' partials
  const int sidx = (tid - 64) >> 6;               // 0..6 (valid for tid>=64)
  const int oslice = sidx + (sidx >= j ? 1 : 0);  // skip own slice

  for (int t = 0; t < TPL; ++t) {
    const float* xrow = xpl + ((size_t)b * TPL + t) * NC + j * SC;
    float xv = (tid < SC) ? xrow[tid] : 0.f;      // in flight during h wait
    float mtv = (tid < 32) ? mask_p[b * TPL + t] : 0.f;
    const unsigned int hseq = (unsigned int)(lbase + t);
    const unsigned int sseq = (unsigned int)(lbase + t + 1);

    __syncthreads();                   // B0: prev-step LDS reads done
    // ---- spin-load h[t] (poll+gather fused), stage x
    if (tid < DD) h_lds[tid] = (t > 0) ? spinload(xch_h_b + tid, hseq) : 0.f;
    if (tid < SC) xsl[tid] = xv;
    __syncthreads();                   // B1: h_lds, xsl ready

    // ---- att GEMV, in-wave (threads 0..255): col=tid>>3, q=tid&7,
    //      interleaved k = i*32 + q*4 (8 x 16B chunks span all 32 banks)
    if (tid < 256) {
      int q = tid & 7;
      float a0 = 0.f, a1 = 0.f;
      #pragma unroll
      for (int i = 0; i < 8; ++i) {
        uint2 w = wat2[i][tid];
        float4 h0 = *(const float4*)&h_lds[i * 32 + q * 4];
        a0 = fmaf(h0.x, bflo(w.x), a0); a1 = fmaf(h0.y, bfhi(w.x), a1);
        a0 = fmaf(h0.z, bflo(w.y), a0); a1 = fmaf(h0.w, bfhi(w.y), a1);
      }
      float p = a0 + a1;
      p += __shfl_xor(p, 1);
      p += __shfl_xor(p, 2);
      p += __shfl_xor(p, 4);
      if (q == 0) hw_att[tid >> 3] = p;
    }
    __syncthreads();                   // B2: hw_att ready

    // ---- scores: 64 tq x 8 subs (4 a each), all 512
    {
      float p = 0.f;
      #pragma unroll
      for (int i = 0; i < 4; ++i) {
        int a = ssub * 4 + i;
        p = fmaf(fast_tanh(qT[a][stq] + xsl[a] + hw_att[a]), waa[a], p);
      }
      sc_part[ssub][stq] = p;
    }
    __syncthreads();                   // B3: sc_part ready

    // ---- merged region (no internal barrier):
    //      tid<64: publish own partial FIRST, then gate GEMV.
    //      tid>=64: gate GEMV (hides score RT), then spin 1 of 7x64 others.
    float hwg;
    if (tid < 64) {
      float s = 0.f;
      #pragma unroll
      for (int q = 0; q < 8; ++q) s += sc_part[q][tid];
      astore64(xch_s_b + (j << 6) + tid, packsv(s, sseq));
    }
    {
      float g0 = 0.f, g1 = 0.f;
      #pragma unroll
      for (int i = 0; i < 16; ++i) {
        int kq = i * 4 + gq;                     // interleaved k-split
        uint2 w = wg_l[i][tid];
        float4 h0 = *(const float4*)&h_lds[kq * 4];
        g0 = fmaf(h0.x, bflo(w.x), g0); g1 = fmaf(h0.y, bfhi(w.x), g1);
        g0 = fmaf(h0.z, bflo(w.y), g0); g1 = fmaf(h0.w, bfhi(w.y), g1);
      }
      hwg = g0 + g1;
      hwg += __shfl_xor(hwg, 1);
      hwg += __shfl_xor(hwg, 2);       // all 4 partners hold full hw_gate[gcol]
    }
    if (tid >= 64) {
      gat[sidx][stq] = spinload(xch_s_b + (oslice << 6) + stq, sseq);
    }
    __syncthreads();                   // B4: gat ready

    // ---- replicated softmax (every wave; alpha in lane regs) + fused pre
    float al;
    {
      float v = 0.f;
      #pragma unroll
      for (int q = 0; q < 8; ++q) v += sc_part[q][lane];
      #pragma unroll
      for (int s = 0; s < 7; ++s) v += gat[s][lane];
      v = (mq > 0.f) ? v : -1e9f;
      float m = v;
      #pragma unroll
      for (int off = 32; off > 0; off >>= 1) m = fmaxf(m, __shfl_xor(m, off));
      float p = __expf(v - m);
      float su = p;
      #pragma unroll
      for (int off = 32; off > 0; off >>= 1) su += __shfl_xor(su, off);
      al = p * __builtin_amdgcn_rcpf(su);        // alpha[lane], every wave
    }
    {
      float d0 = 0.f, d1 = 0.f;
      #pragma unroll
      for (int i = 0; i < 8; ++i) {
        int tw = gq * 8 + i;
        unsigned int v = vl_l[i][tid];
        float alo = __shfl(al, 2 * tw);
        float ahi = __shfl(al, 2 * tw + 1);
        d0 = fmaf(alo, bflo(v), d0);
        d1 = fmaf(ahi, bfhi(v), d1);
      }
      float d = d0 + d1;
      d += __shfl_xor(d, 1);
      d += __shfl_xor(d, 2);
      if (gq == 0)
        pre_s[gcol] = hwg + d + xsl[32 + gcol] + bias_s[gcol];
    }
    __syncthreads();                   // B5: pre ready

    // ---- gates + state for own 32 h-elems; publish seq-stamped h slice
    if (tid < 32) {
      float f  = pre_s[tid];
      float ii = pre_s[32 + tid];
      float oo = pre_s[64 + tid];
      float g  = pre_s[96 + tid];
      int m = (j << 5) + tid;
      float c0 = cv, h0 = h_lds[m];
      float c1 = fast_sigmoid(f) * c0 + fast_sigmoid(ii) * fast_tanh(g);
      c1 = c1 * mtv + c0 * (1.f - mtv);
      float h1 = fast_sigmoid(oo) * fast_tanh(c1);
      h1 = h1 * mtv + h0 * (1.f - mtv);
      cv = c1;
      astore64(xch_h_b + m, packsv(h1, sseq));
      out[((size_t)b * TPL + t) * DD + m] = h1;
    }
    // no trailing barrier: next iteration's B0 orders LDS reuse
  }
}

// -----------------------------------------------------------------------------
extern "C" void kernel_launch(void* const* d_in, const int* in_sizes, int n_in,
                              void* d_out, int out_size, void* d_ws, size_t ws_size,
                              hipStream_t stream) {
  const float* input_p  = (const float*)d_in[0];
  const float* mask_p   = (const float*)d_in[1];
  const float* input_q  = (const float*)d_in[2];
  const float* mask_q   = (const float*)d_in[3];
  const float* W_att_p  = (const float*)d_in[4];
  const float* W_att_q  = (const float*)d_in[5];
  const float* W_att_r  = (const float*)d_in[6];
  const float* w_att    = (const float*)d_in[7];
  const float* W_lstm   = (const float*)d_in[8];
  const float* bias_f   = (const float*)d_in[9];
  const float* bias_iog = (const float*)d_in[10];
  float* out = (float*)d_out;
  float* ws  = (float*)d_ws;
  (void)ws_size; (void)in_sizes; (void)n_in; (void)out_size;

  const size_t SZ_XPL  = (size_t)NB * TPL * NC;
  const size_t SZ_QV   = (size_t)NB * TQL * NC;
  const size_t SZ_W    = (size_t)DD * NC;
  const size_t SZ_ATTL = (size_t)NS * 8 * 256;    // uint2 per layer
  const size_t SZ_GATL = (size_t)NS * 16 * 512;   // uint2 per layer

  float* ws_xpl = ws;
  float* ws_qv  = ws_xpl + SZ_XPL;
  float* ws_wx  = ws_qv  + 2 * SZ_QV;
  float* ws_wqv = ws_wx  + 2 * SZ_W;
  float* ws_o0  = ws_wqv + 2 * SZ_W;
  uint2* ws_attl = (uint2*)(ws_o0 + (size_t)NB * TPL * DD);
  uint2* ws_gatl = ws_attl + 2 * SZ_ATTL;
  u64*   ws_xs   = (u64*)(ws_gatl + 2 * SZ_GATL);    // [NB][8][64] seq-stamped
  u64*   ws_xh   = ws_xs + NB * NS * TQL;            // [NB][256]  seq-stamped

  dim3 gpack((DD * NC + 255) / 256, 2);
  pack_weights<<<gpack, 256, 0, stream>>>(W_att_p, W_att_q, W_lstm, ws_wx, ws_wqv);
  pack_attl<<<(2 * NS * 8 * 256 + 255) / 256, 256, 0, stream>>>(W_att_r, ws_attl);
  pack_gatel<<<(2 * NS * 16 * 512 + 255) / 256, 256, 0, stream>>>(W_lstm, ws_gatl);
  hipMemsetAsync(ws_xs, 0, (NB * NS * TQL + NB * DD) * sizeof(u64), stream);

  for (int d = 0; d < 2; ++d) {
    dim3 g(NC / 64, (NB * TQL) / 64);
    sgemm<false><<<g, 256, 0, stream>>>(input_q, ws_wqv + d * SZ_W, ws_qv + d * SZ_QV);
  }

  // layer 0
  {
    dim3 g(NC / 64, (NB * TPL) / 64);
    sgemm<true><<<g, 256, 0, stream>>>(input_p, ws_wx, ws_xpl);
    scan<<<NB * NS, 512, 0, stream>>>(ws_xpl, ws_qv, ws_attl, ws_gatl,
                                      w_att, bias_f, bias_iog, mask_p, mask_q,
                                      ws_xs, ws_xh, ws_o0, 0);
  }
  // layer 1
  {
    dim3 g(NC / 64, (NB * TPL) / 64);
    sgemm<true><<<g, 256, 0, stream>>>(ws_o0, ws_wx + SZ_W, ws_xpl);
    scan<<<NB * NS, 512, 0, stream>>>(ws_xpl, ws_qv + SZ_QV, ws_attl + SZ_ATTL,
                                      ws_gatl + SZ_GATL, w_att + DD, bias_f + DD,
                                      bias_iog + 3 * DD, mask_p, mask_q,
                                      ws_xs, ws_xh, out, TPL);
  }
}

// Round 18
// 3998.689 us; speedup vs baseline: 1.3969x; 1.0774x over previous
//
#include <hip/hip_runtime.h>
#include <hip/hip_bf16.h>

// StackedMatchLSTM on MI355X — r14 structure (proven 4.02 ms) with one
// change: score partials gathered into a separate array (sc_gat), removing
// the write-after-read hazard barrier (9 -> 8 barriers/step).
// B=32, TP=512, TQ=64, DP=DQ=H=AH=256, NL=2.
// Scan: 256 WGs (8 slices x 32 batches) x 512 threads. Slice j owns 32 att
// cols + 128 gate cols; weights LDS-resident (bf16, consumption-ordered
// [iter][tid] layouts -> zero bank conflicts). Per step: spin-load h ->
// att GEMV -> scores -> publish scores -> gate GEMV (hides score RT) ->
// spin-load scores (into sc_gat) -> softmax -> pre -> gates -> publish h.
// Exchange: seq-stamped (bits,seq) 8B relaxed agent atomics; consumers spin
// on their own element until seq matches — self-validating, no ordering
// requirements (proven r14-r17).

#define NB 32
#define TPL 512
#define TQL 64
#define DD 256      // DP = DQ = H = AH
#define H4 1024     // 4*H
#define NC 1280     // AH + 4H
#define NS 8        // slices per batch
#define SC 160      // xpl cols per slice = 32 att + 128 gate
#define GC 128      // gate cols per slice

typedef unsigned long long u64;

__device__ __forceinline__ float fast_tanh(float x) {
  float xc = fminf(fmaxf(x, -9.f), 9.f);
  float e = __expf(2.f * xc);
  return (e - 1.f) * __builtin_amdgcn_rcpf(e + 1.f);
}
__device__ __forceinline__ float fast_sigmoid(float x) {
  return __builtin_amdgcn_rcpf(1.f + __expf(-x));
}
__device__ __forceinline__ float bflo(unsigned int w) { return __uint_as_float(w << 16); }
__device__ __forceinline__ float bfhi(unsigned int w) { return __uint_as_float(w & 0xffff0000u); }
__device__ __forceinline__ unsigned int packbf(float a, float b) {
  unsigned int lo = __hip_bfloat16_raw(__float2bfloat16(a)).x;
  unsigned int hi = __hip_bfloat16_raw(__float2bfloat16(b)).x;
  return lo | (hi << 16);
}

// ---- seq-stamped payload exchange (relaxed agent atomics, LLC-coherent) -----
__device__ __forceinline__ u64 aload64(const u64* p) {
  return __hip_atomic_load(p, __ATOMIC_RELAXED, __HIP_MEMORY_SCOPE_AGENT);
}
__device__ __forceinline__ void astore64(u64* p, u64 v) {
  __hip_atomic_store(p, v, __ATOMIC_RELAXED, __HIP_MEMORY_SCOPE_AGENT);
}
__device__ __forceinline__ u64 packsv(float val, unsigned int seq) {
  return ((u64)seq << 32) | (u64)__float_as_uint(val);
}
__device__ __forceinline__ float spinload(const u64* p, unsigned int seq) {
  u64 v = aload64(p);
  int guard = 0;
  while ((unsigned int)(v >> 32) != seq) {
    __builtin_amdgcn_s_sleep(1);
    v = aload64(p);
    if (++guard > (1 << 24)) break;   // bail instead of hanging the harness
  }
  return __uint_as_float((unsigned int)v);
}

// permuted xpl cols: slice-major blocks of 160: 32 att | f|i|o|g x32
__device__ __forceinline__ int perm_col(int c) {
  if (c < DD) return (c >> 5) * SC + (c & 31);
  int cc = c - DD;
  int g = cc >> 8;          // 0..3 = f,i,o,g
  int m = cc & 255;         // h-elem
  return (m >> 5) * SC + 32 + (g << 5) + (m & 31);
}

// ---- weight prep ------------------------------------------------------------
__global__ __launch_bounds__(256) void pack_weights(
    const float* __restrict__ Wp, const float* __restrict__ Wq,
    const float* __restrict__ Wl,
    float* __restrict__ wx, float* __restrict__ wqv)
{
  int d = blockIdx.y;
  int idx = blockIdx.x * 256 + threadIdx.x;
  if (idx >= DD * NC) return;
  int k = idx / NC, j = idx % NC;
  int o = d * DD * NC + idx;
  const float* Wld = Wl + (size_t)d * 768 * H4;
  if (j < DD) {
    int s = d * DD * DD + k * DD + j;
    wx[o] = Wp[s]; wqv[o] = Wq[s];
  } else {
    int c = j - DD;
    wx[o]  = Wld[(size_t)k * H4 + c];
    wqv[o] = Wld[(size_t)(DD + k) * H4 + c];
  }
}

// attl, consumption order: [(d*8+j)][i(4)][slot(512)], slot = ak*32 + acol.
// uint2 = k's {4kq..4kq+3} of col (32j+acol), kq = ak*4 + i.
__global__ __launch_bounds__(256) void pack_attl(
    const float* __restrict__ Wr, uint2* __restrict__ attl)
{
  int idx = blockIdx.x * 256 + threadIdx.x;       // 2*8*4*512 = 32768
  if (idx >= 2 * NS * 4 * 512) return;
  int slot = idx & 511; int r = idx >> 9;
  int i = r & 3; r >>= 2;
  int j = r & 7; int d = r >> 3;
  int acol = slot & 31, ak = slot >> 5;
  int kq = ak * 4 + i;
  int col = (j << 5) + acol;
  float v[4];
  #pragma unroll
  for (int kr = 0; kr < 4; ++kr)
    v[kr] = Wr[((size_t)d * DD + kq * 4 + kr) * DD + col];
  attl[idx] = make_uint2(packbf(v[0], v[1]), packbf(v[2], v[3]));
}

// gatel, consumption order: [(d*8+j)][i(16)][slot(512)], slot: gcol=slot>>2,
// gq=slot&3. uint2 = k's {4kq..4kq+3} of gate col gcol, kq = i*4 + gq.
__global__ __launch_bounds__(256) void pack_gatel(
    const float* __restrict__ Wl, uint2* __restrict__ gatel)
{
  int idx = blockIdx.x * 256 + threadIdx.x;       // 2*8*16*512 = 131072
  if (idx >= 2 * NS * 16 * 512) return;
  int slot = idx & 511; int r = idx >> 9;
  int i = r & 15; r >>= 4;
  int j = r & 7; int d = r >> 3;
  int gcol = slot >> 2, gq = slot & 3;
  int kq = i * 4 + gq;
  int g = gcol >> 5, pos = gcol & 31;
  float v[4];
  #pragma unroll
  for (int kr = 0; kr < 4; ++kr) {
    int k = kq * 4 + kr;
    v[kr] = Wl[((size_t)d * 768 + 512 + k) * H4 + (g << 8) + (j << 5) + pos];
  }
  gatel[idx] = make_uint2(packbf(v[0], v[1]), packbf(v[2], v[3]));
}

// ---- C[M][1280] = A[M][256] @ B[256][1280], fp32 ----------------------------
template <bool PERM>
__global__ __launch_bounds__(256) void sgemm(
    const float* __restrict__ A, const float* __restrict__ Bm,
    float* __restrict__ C)
{
  __shared__ float As[16][65];
  __shared__ float Bs[16][64];
  int tid = threadIdx.x;
  int tx = tid & 15, ty = tid >> 4;
  int col0 = blockIdx.x * 64, row0 = blockIdx.y * 64;
  float acc[4][4] = {};
  for (int kt = 0; kt < DD; kt += 16) {
    #pragma unroll
    for (int i = 0; i < 4; ++i) {
      int e = tid + i * 256;
      As[e & 15][e >> 4] = A[(size_t)(row0 + (e >> 4)) * DD + kt + (e & 15)];
      Bs[e >> 6][e & 63] = Bm[(size_t)(kt + (e >> 6)) * NC + col0 + (e & 63)];
    }
    __syncthreads();
    #pragma unroll
    for (int kk = 0; kk < 16; ++kk) {
      float a[4], bv[4];
      #pragma unroll
      for (int i = 0; i < 4; ++i) a[i] = As[kk][ty * 4 + i];
      #pragma unroll
      for (int jj = 0; jj < 4; ++jj) bv[jj] = Bs[kk][tx * 4 + jj];
      #pragma unroll
      for (int i = 0; i < 4; ++i)
        #pragma unroll
        for (int jj = 0; jj < 4; ++jj)
          acc[i][jj] = fmaf(a[i], bv[jj], acc[i][jj]);
    }
    __syncthreads();
  }
  #pragma unroll
  for (int i = 0; i < 4; ++i)
    #pragma unroll
    for (int jj = 0; jj < 4; ++jj) {
      int c = col0 + tx * 4 + jj;
      int cc = PERM ? perm_col(c) : c;
      C[(size_t)(row0 + ty * 4 + i) * NC + cc] = acc[i][jj];
    }
}

// ---- scan: 256 WGs x 512 threads, weights LDS-resident ----------------------
__global__ __launch_bounds__(512, 1) void scan(
    const float* __restrict__ xpl,    // [NB*TP][NC] permuted cols
    const float* __restrict__ qv,     // [NB*TQ][NC] plain (this layer)
    const uint2* __restrict__ attl,   // this layer's [8][4][512]
    const uint2* __restrict__ gatel,  // this layer's [8][16][512]
    const float* __restrict__ wa,     // [256]
    const float* __restrict__ bias_f,
    const float* __restrict__ bias_iog,
    const float* __restrict__ mask_p,
    const float* __restrict__ mask_q,
    u64* __restrict__ xch_s,          // [NB][NS][64] seq-stamped scores
    u64* __restrict__ xch_h,          // [NB][256]  seq-stamped h
    float* __restrict__ out,          // [NB*TP][256]
    int lbase)                        // layer*TPL
{
  const int bid = blockIdx.x;
  const int j = bid & 7, b = bid >> 3;
  const int tid = threadIdx.x;
  const int lane = tid & 63;

  __shared__ uint2 wg_l[16][512];        // 64 KB gate weights, [iter][tid]
  __shared__ uint2 wat_l[4][512];        // 16 KB att weights, [iter][tid]
  __shared__ unsigned int vl_l[8][512];  // 16 KB Vl bf16 pairs, [iter][tid]
  __shared__ float qT[32][65];           //  8.3 KB qWq^T (own att cols)
  __shared__ __align__(16) float h_lds[DD];
  __shared__ float xsl[SC];
  __shared__ float hw_att[32], waa[32], c_sh[32];
  __shared__ float att_part[16][33];
  __shared__ float sc_part[8][TQL];      // own-slice score sub-partials
  __shared__ float sc_gat[8][TQL];       // gathered all-slice partials
  __shared__ float al_s[TQL];
  __shared__ float pre_s[GC], bias_s[GC];

  const float* qv_b = qv + (size_t)b * TQL * NC;
  u64* xch_s_b = xch_s + b * (NS * TQL);
  u64* xch_h_b = xch_h + b * DD;

  // ---- one-time preload: weights + per-batch activations into LDS
  {
    const uint2* gp = gatel + (size_t)j * 16 * 512;
    for (int i = tid; i < 16 * 512; i += 512) wg_l[i >> 9][i & 511] = gp[i];
    const uint2* ap = attl + (size_t)j * 4 * 512;
    for (int i = tid; i < 4 * 512; i += 512) wat_l[i >> 9][i & 511] = ap[i];
    for (int i = tid; i < TQL * 32; i += 512) {
      int tq = i >> 5, a = i & 31;
      qT[a][tq] = qv_b[(size_t)tq * NC + (j << 5) + a];
    }
    // vl_l[ii][slot]: slot -> gcol=slot>>2, gq=slot&3; tw = gq*8+ii
    for (int f = tid; f < 8 * 512; f += 512) {
      int ii = f >> 9, slot = f & 511;
      int gcol = slot >> 2, gq = slot & 3;
      int tw = gq * 8 + ii;
      int g = gcol >> 5, m = (j << 5) + (gcol & 31);
      float v0 = qv_b[(size_t)(2 * tw) * NC + DD + (g << 8) + m];
      float v1 = qv_b[(size_t)(2 * tw + 1) * NC + DD + (g << 8) + m];
      vl_l[ii][slot] = packbf(v0, v1);
    }
    if (tid < 32) { waa[tid] = wa[(j << 5) + tid]; c_sh[tid] = 0.f; }
    if (tid < GC) {
      int g = tid >> 5, m = (j << 5) + (tid & 31);
      bias_s[tid] = (g == 0) ? bias_f[m] : bias_iog[((g - 1) << 8) + m];
    }
  }
  float mq = mask_q[b * TQL + lane];    // softmax mask, lane = tq (wave 0 uses)
  __syncthreads();

  // role indices
  const int ak = tid >> 5;                        // att: 16-way k-split
  const int stq = tid & 63, ssub = tid >> 6;      // scores: 8 subs x 4 cols
  const int gcol = tid >> 2, gq = tid & 3;        // gate/pre: 4-way k/tq split

  for (int t = 0; t < TPL; ++t) {
    const float* xrow = xpl + ((size_t)b * TPL + t) * NC + j * SC;
    float xv = (tid < SC) ? xrow[tid] : 0.f;      // in flight during h wait
    const unsigned int hseq = (unsigned int)(lbase + t);       // h after t-1
    const unsigned int sseq = (unsigned int)(lbase + t + 1);   // this step

    __syncthreads();                   // B0: prev-step LDS reads done
    // ---- spin-load h[t] (poll+gather fused: one LLC round trip)
    if (tid < DD) h_lds[tid] = (t > 0) ? spinload(xch_h_b + tid, hseq) : 0.f;
    if (tid < SC) xsl[tid] = xv;
    __syncthreads();                   // B1: h_lds, xsl ready

    // ---- att GEMV from LDS: 32 cols x 16-way k-split (16 k each)
    {
      float a0 = 0.f, a1 = 0.f;
      #pragma unroll
      for (int i = 0; i < 4; ++i) {
        int kq = ak * 4 + i;
        uint2 w = wat_l[i][tid];
        float4 h0 = *(const float4*)&h_lds[kq * 4];
        a0 = fmaf(h0.x, bflo(w.x), a0); a1 = fmaf(h0.y, bfhi(w.x), a1);
        a0 = fmaf(h0.z, bflo(w.y), a0); a1 = fmaf(h0.w, bfhi(w.y), a1);
      }
      att_part[ak][tid & 31] = a0 + a1;
    }
    __syncthreads();                   // B2
    if (tid < 32) {
      float s = 0.f;
      #pragma unroll
      for (int i = 0; i < 16; ++i) s += att_part[i][tid];
      hw_att[tid] = s;
    }
    __syncthreads();                   // B3: hw_att ready

    // ---- scores: 64 tq x 8 subs (4 a each)
    {
      float p = 0.f;
      #pragma unroll
      for (int i = 0; i < 4; ++i) {
        int a = ssub * 4 + i;
        p = fmaf(fast_tanh(qT[a][stq] + xsl[a] + hw_att[a]), waa[a], p);
      }
      sc_part[ssub][stq] = p;
    }
    __syncthreads();                   // B4
    // ---- publish score partial (wave 0), seq-stamped
    if (tid < TQL) {
      float s = 0.f;
      #pragma unroll
      for (int q = 0; q < 8; ++q) s += sc_part[q][tid];
      astore64(xch_s_b + (j << 6) + tid, packsv(s, sseq));
    }

    // ---- gate GEMV from LDS (all 512): hides score flight
    float hwg;
    {
      float g0 = 0.f, g1 = 0.f;
      #pragma unroll
      for (int i = 0; i < 16; ++i) {
        int kq = i * 4 + gq;                     // interleaved k-split
        uint2 w = wg_l[i][tid];
        float4 h0 = *(const float4*)&h_lds[kq * 4];
        g0 = fmaf(h0.x, bflo(w.x), g0); g1 = fmaf(h0.y, bfhi(w.x), g1);
        g0 = fmaf(h0.z, bflo(w.y), g0); g1 = fmaf(h0.w, bfhi(w.y), g1);
      }
      hwg = g0 + g1;
      hwg += __shfl_xor(hwg, 1);
      hwg += __shfl_xor(hwg, 2);       // all 4 partners hold full hw_gate[gcol]
    }

    // ---- spin-load score partials into sc_gat (separate array -> no
    //      write-after-read hazard with the publisher; B5 of r14 removed)
    sc_gat[ssub][stq] = spinload(xch_s_b + (ssub << 6) + stq, sseq);
    __syncthreads();                   // B5: sc_gat complete
    if (tid < TQL) {
      float v = 0.f;
      #pragma unroll
      for (int q = 0; q < 8; ++q) v += sc_gat[q][tid];
      v = (mq > 0.f) ? v : -1e9f;
      float m = v;
      #pragma unroll
      for (int off = 32; off > 0; off >>= 1) m = fmaxf(m, __shfl_xor(m, off));
      float p = __expf(v - m);
      float su = p;
      #pragma unroll
      for (int off = 32; off > 0; off >>= 1) su += __shfl_xor(su, off);
      al_s[tid] = p * __builtin_amdgcn_rcpf(su);
    }
    __syncthreads();                   // B6: al_s ready

    // ---- pre: alpha@Vl (4-way tq split) + hwg + x + bias
    {
      float d0 = 0.f, d1 = 0.f;
      #pragma unroll
      for (int i = 0; i < 8; ++i) {
        int tw = gq * 8 + i;
        unsigned int v = vl_l[i][tid];
        d0 = fmaf(al_s[2 * tw], bflo(v), d0);
        d1 = fmaf(al_s[2 * tw + 1], bfhi(v), d1);
      }
      float d = d0 + d1;
      d += __shfl_xor(d, 1);
      d += __shfl_xor(d, 2);
      if (gq == 0)
        pre_s[gcol] = hwg + d + xsl[32 + gcol] + bias_s[gcol];
    }
    __syncthreads();                   // B7: pre ready

    // ---- gates + state for own 32 h-elems; publish seq-stamped h slice
    if (tid < 32) {
      float f  = pre_s[tid];
      float ii = pre_s[32 + tid];
      float oo = pre_s[64 + tid];
      float g  = pre_s[96 + tid];
      float mtv = mask_p[b * TPL + t];
      int m = (j << 5) + tid;
      float c0 = c_sh[tid], h0 = h_lds[m];
      float c1 = fast_sigmoid(f) * c0 + fast_sigmoid(ii) * fast_tanh(g);
      c1 = c1 * mtv + c0 * (1.f - mtv);
      float h1 = fast_sigmoid(oo) * fast_tanh(c1);
      h1 = h1 * mtv + h0 * (1.f - mtv);
      c_sh[tid] = c1;
      astore64(xch_h_b + m, packsv(h1, sseq));
      out[((size_t)b * TPL + t) * DD + m] = h1;
    }
    // no trailing barrier: next iteration's B0 orders LDS reuse
  }
}

// -----------------------------------------------------------------------------
extern "C" void kernel_launch(void* const* d_in, const int* in_sizes, int n_in,
                              void* d_out, int out_size, void* d_ws, size_t ws_size,
                              hipStream_t stream) {
  const float* input_p  = (const float*)d_in[0];
  const float* mask_p   = (const float*)d_in[1];
  const float* input_q  = (const float*)d_in[2];
  const float* mask_q   = (const float*)d_in[3];
  const float* W_att_p  = (const float*)d_in[4];
  const float* W_att_q  = (const float*)d_in[5];
  const float* W_att_r  = (const float*)d_in[6];
  const float* w_att    = (const float*)d_in[7];
  const float* W_lstm   = (const float*)d_in[8];
  const float* bias_f   = (const float*)d_in[9];
  const float* bias_iog = (const float*)d_in[10];
  float* out = (float*)d_out;
  float* ws  = (float*)d_ws;
  (void)ws_size; (void)in_sizes; (void)n_in; (void)out_size;

  const size_t SZ_XPL  = (size_t)NB * TPL * NC;
  const size_t SZ_QV   = (size_t)NB * TQL * NC;
  const size_t SZ_W    = (size_t)DD * NC;
  const size_t SZ_ATTL = (size_t)NS * 4 * 512;    // uint2 per layer
  const size_t SZ_GATL = (size_t)NS * 16 * 512;   // uint2 per layer

  float* ws_xpl = ws;
  float* ws_qv  = ws_xpl + SZ_XPL;
  float* ws_wx  = ws_qv  + 2 * SZ_QV;
  float* ws_wqv = ws_wx  + 2 * SZ_W;
  float* ws_o0  = ws_wqv + 2 * SZ_W;
  uint2* ws_attl = (uint2*)(ws_o0 + (size_t)NB * TPL * DD);
  uint2* ws_gatl = ws_attl + 2 * SZ_ATTL;
  u64*   ws_xs   = (u64*)(ws_gatl + 2 * SZ_GATL);    // [NB][8][64] seq-stamped
  u64*   ws_xh   = ws_xs + NB * NS * TQL;            // [NB][256]  seq-stamped

  dim3 gpack((DD * NC + 255) / 256, 2);
  pack_weights<<<gpack, 256, 0, stream>>>(W_att_p, W_att_q, W_lstm, ws_wx, ws_wqv);
  pack_attl<<<(2 * NS * 4 * 512 + 255) / 256, 256, 0, stream>>>(W_att_r, ws_attl);
  pack_gatel<<<(2 * NS * 16 * 512 + 255) / 256, 256, 0, stream>>>(W_lstm, ws_gatl);
  hipMemsetAsync(ws_xs, 0, (NB * NS * TQL + NB * DD) * sizeof(u64), stream);

  for (int d = 0; d < 2; ++d) {
    dim3 g(NC / 64, (NB * TQL) / 64);
    sgemm<false><<<g, 256, 0, stream>>>(input_q, ws_wqv + d * SZ_W, ws_qv + d * SZ_QV);
  }

  // layer 0
  {
    dim3 g(NC / 64, (NB * TPL) / 64);
    sgemm<true><<<g, 256, 0, stream>>>(input_p, ws_wx, ws_xpl);
    scan<<<NB * NS, 512, 0, stream>>>(ws_xpl, ws_qv, ws_attl, ws_gatl,
                                      w_att, bias_f, bias_iog, mask_p, mask_q,
                                      ws_xs, ws_xh, ws_o0, 0);
  }
  // layer 1
  {
    dim3 g(NC / 64, (NB * TPL) / 64);
    sgemm<true><<<g, 256, 0, stream>>>(ws_o0, ws_wx + SZ_W, ws_xpl);
    scan<<<NB * NS, 512, 0, stream>>>(ws_xpl, ws_qv + SZ_QV, ws_attl + SZ_ATTL,
                                      ws_gatl + SZ_GATL, w_att + DD, bias_f + DD,
                                      bias_iog + 3 * DD, mask_p, mask_q,
                                      ws_xs, ws_xh, out, TPL);
  }
}